// Round 13
// baseline (1373.166 us; speedup 1.0000x reference)
//
#include <hip/hip_runtime.h>
#include <cmath>

#define B_ 8
#define T_ 64
#define N_ 256
#define F_ 64
#define C_ 128
#define O_ 32
#define H_ 1024
#define NC_ 16

typedef __attribute__((ext_vector_type(8))) short bf16x8;
typedef __attribute__((ext_vector_type(4))) float f32x4;

__device__ __forceinline__ float sigf(float x){ return 1.f/(1.f+expf(-x)); }

__device__ __forceinline__ unsigned short f2bf(float f){
  unsigned int u = __float_as_uint(f);
  u += 0x7fff + ((u >> 16) & 1);          // round-to-nearest-even
  return (unsigned short)(u >> 16);
}
__device__ __forceinline__ float bf2f(unsigned short s){
  return __uint_as_float(((unsigned int)s) << 16);
}

__device__ __forceinline__ void gload16(const void* g, void* l){
  __builtin_amdgcn_global_load_lds((const __attribute__((address_space(1))) void*)g,
                                   (__attribute__((address_space(3))) void*)l, 16, 0, 0);
}

__device__ __forceinline__ bf16x8 cvt8(const float* p){
  float4 a = *(const float4*)p, b = *(const float4*)(p + 4);
  bf16x8 r;
  r[0] = (short)f2bf(a.x); r[1] = (short)f2bf(a.y);
  r[2] = (short)f2bf(a.z); r[3] = (short)f2bf(a.w);
  r[4] = (short)f2bf(b.x); r[5] = (short)f2bf(b.y);
  r[6] = (short)f2bf(b.z); r[7] = (short)f2bf(b.w);
  return r;
}

// tag line i: 0..7 = layer1 blocks, 8..23 = layer2 blocks. 1 word / 128B line.
#define TAGW(i) ((i) << 5)
#define NTAGW 1024
#define L1B 8
#define L2B 16

// ---------------- K0: attr_eff[g][j][i] ----------------
__global__ __launch_bounds__(256) void attr_kernel(const float* __restrict__ V, float* __restrict__ attr){
  __shared__ float sv[32][33];
  __shared__ float selfv[32];
  int g = blockIdx.x, tid = threadIdx.x;
  for (int idx = tid; idx < 1024; idx += 256){
    int j = idx >> 5, i = idx & 31;
    sv[j][i] = sigf(V[(size_t)(g*32 + j)*256 + g*32 + i]);
  }
  __syncthreads();
  if (tid < 32){
    float s = 0.f;
    for (int j = 0; j < 32; ++j) if (j != tid) s += sv[j][tid];
    selfv[tid] = s * (1.f/31.f);
  }
  __syncthreads();
  for (int idx = tid; idx < 1024; idx += 256){
    int j = idx >> 5, i = idx & 31;
    attr[g*1024 + idx] = (j == i) ? selfv[i] : sv[j][i];
  }
}

// ---------------- prep: Wcomb = Wfc@Wl (bf16), bias_comb, Wlr_bf ----------------
__global__ __launch_bounds__(256) void prep_kernel(
    const float* __restrict__ Wl, const float* __restrict__ Wr,
    const float* __restrict__ bl, const float* __restrict__ gb,
    const float* __restrict__ Wfc, const float* __restrict__ bfc,
    unsigned short* __restrict__ wcomb,   // [32][64] bf16
    float* __restrict__ bias_comb,        // [32]
    unsigned short* __restrict__ wlr){    // [256][64] bf16
  __shared__ float wls[8192], wfcs[4096];
  int tid = threadIdx.x;
  for (int i = tid; i < 8192; i += 256) wls[i] = Wl[i];
  for (int i = tid; i < 4096; i += 256) wfcs[i] = Wfc[i];
  __syncthreads();
  for (int idx = tid; idx < 2048; idx += 256){
    int o = idx >> 6, f = idx & 63;
    float acc = 0.f;
    for (int c = 0; c < 128; ++c) acc = fmaf(wfcs[o*128 + c], wls[c*64 + f], acc);
    wcomb[idx] = f2bf(acc);
  }
  if (tid < 32){
    float acc = bfc[tid];
    for (int c = 0; c < 128; ++c) acc = fmaf(wfcs[tid*128 + c], bl[c] + gb[c], acc);
    bias_comb[tid] = acc;
  }
  for (int idx = tid; idx < 16384; idx += 256){
    int r = idx >> 6, f = idx & 63;
    wlr[idx] = f2bf(r < 128 ? wls[r*64 + f] : Wr[(r-128)*64 + f]);
  }
}

// ---------------- gemm_proj0: gl0/gr0 = X0 @ [Wl;Wr]^T (b==0 slice) ----------------
__global__ __launch_bounds__(256) void gemm_proj0(
    const float* __restrict__ X, const unsigned short* __restrict__ wlr,
    const float* __restrict__ bl, const float* __restrict__ br,
    float* __restrict__ gl0, float* __restrict__ gr0){
  int tid = threadIdx.x;
  int lane = tid & 63, w = tid >> 6;
  int lr = lane & 15, ko = lane >> 4;
  int row = blockIdx.x*64 + w*16 + lr;

  bf16x8 af[2];
  #pragma unroll
  for (int ks = 0; ks < 2; ++ks)
    af[ks] = cvt8(&X[(size_t)row*64 + ks*32 + ko*8]);

  f32x4 zero = {0.f,0.f,0.f,0.f};
  #pragma unroll 4
  for (int nt = 0; nt < 16; ++nt){
    f32x4 acc = zero;
    #pragma unroll
    for (int ks = 0; ks < 2; ++ks){
      bf16x8 bv = *(const bf16x8*)&wlr[(size_t)(nt*16 + lr)*64 + ks*32 + ko*8];
      acc = __builtin_amdgcn_mfma_f32_16x16x32_bf16(af[ks], bv, acc, 0, 0, 0);
    }
    int col = nt*16 + lr;
    #pragma unroll
    for (int v = 0; v < 4; ++v){
      int orow = blockIdx.x*64 + w*16 + ko*4 + v;
      if (col < 128) gl0[(size_t)orow*128 + col]        = acc[v] + bl[col];
      else           gr0[(size_t)orow*128 + (col-128)]  = acc[v] + br[col-128];
    }
  }
}

// ---------------- gemm_rest: xl(b>0) = X @ Wcomb^T + bias_comb ----------------
__global__ __launch_bounds__(256) void gemm_rest(
    const float* __restrict__ X, const unsigned short* __restrict__ wcomb,
    const float* __restrict__ bias_comb, unsigned short* __restrict__ xl){
  int tid = threadIdx.x;
  int lane = tid & 63, w = tid >> 6;
  int lr = lane & 15, ko = lane >> 4;
  int r0 = 16384 + blockIdx.x*256 + w*64;

  bf16x8 bv[2][2];
  #pragma unroll
  for (int nt = 0; nt < 2; ++nt)
    #pragma unroll
    for (int ks = 0; ks < 2; ++ks)
      bv[nt][ks] = *(const bf16x8*)&wcomb[(size_t)(nt*16 + lr)*64 + ks*32 + ko*8];

  f32x4 zero = {0.f,0.f,0.f,0.f};
  #pragma unroll
  for (int mt = 0; mt < 4; ++mt){
    int row = r0 + mt*16 + lr;
    bf16x8 af[2];
    #pragma unroll
    for (int ks = 0; ks < 2; ++ks)
      af[ks] = cvt8(&X[(size_t)row*64 + ks*32 + ko*8]);
    f32x4 acc0 = zero, acc1 = zero;
    #pragma unroll
    for (int ks = 0; ks < 2; ++ks){
      acc0 = __builtin_amdgcn_mfma_f32_16x16x32_bf16(af[ks], bv[0][ks], acc0, 0, 0, 0);
      acc1 = __builtin_amdgcn_mfma_f32_16x16x32_bf16(af[ks], bv[1][ks], acc1, 0, 0, 0);
    }
    #pragma unroll
    for (int v = 0; v < 4; ++v){
      int orow = r0 + mt*16 + ko*4 + v;
      xl[(size_t)orow*32 + lr]      = f2bf(acc0[v] + bias_comb[lr]);
      xl[(size_t)orow*32 + 16 + lr] = f2bf(acc1[v] + bias_comb[16 + lr]);
    }
  }
}

// ---------------- K2: attention for b==0 (+ fused fc) ----------------
__global__ __launch_bounds__(256) void attn_kernel(
    const float* __restrict__ gl0, const float* __restrict__ gr0,
    const float* __restrict__ attr, const float* __restrict__ we, const float* __restrict__ att,
    const float* __restrict__ gbias, const float* __restrict__ Wfc, const float* __restrict__ bfc,
    unsigned short* __restrict__ xl){
  __shared__ float gls[32*129], grs[32*129], os_[32*129], Wfcs[32*129];
  __shared__ float ae[32*33], Ss[32*33];
  __shared__ float wes[128], atts[128];
  int tid = threadIdx.x, blk = blockIdx.x;
  int g = blk & 7, t = blk >> 3;

  const float* glp = gl0 + ((size_t)t*N_ + g*32)*C_;
  const float* grp = gr0 + ((size_t)t*N_ + g*32)*C_;
  for (int idx = tid; idx < 4096; idx += 256){
    int n = idx >> 7, c = idx & 127;
    gls[n*129 + c]  = glp[idx];
    grs[n*129 + c]  = grp[idx];
    Wfcs[n*129 + c] = Wfc[idx];
  }
  for (int idx = tid; idx < 1024; idx += 256) ae[(idx>>5)*33 + (idx&31)] = attr[g*1024 + idx];
  if (tid < 128){ wes[tid] = we[tid]; atts[tid] = att[tid]; }
  __syncthreads();

  int i = tid >> 3, jb = (tid & 7) * 4;
  float a0 = ae[(jb+0)*33 + i], a1 = ae[(jb+1)*33 + i], a2 = ae[(jb+2)*33 + i], a3 = ae[(jb+3)*33 + i];
  float s0 = 0.f, s1 = 0.f, s2 = 0.f, s3 = 0.f;
  for (int cc = 0; cc < 128; ++cc){
    float grv = grs[i*129 + cc];
    float wv = wes[cc], av = atts[cc];
    float p0 = gls[(jb+0)*129 + cc] + grv + a0*wv;
    float p1 = gls[(jb+1)*129 + cc] + grv + a1*wv;
    float p2 = gls[(jb+2)*129 + cc] + grv + a2*wv;
    float p3 = gls[(jb+3)*129 + cc] + grv + a3*wv;
    p0 = p0 > 0.f ? p0 : 0.2f*p0;
    p1 = p1 > 0.f ? p1 : 0.2f*p1;
    p2 = p2 > 0.f ? p2 : 0.2f*p2;
    p3 = p3 > 0.f ? p3 : 0.2f*p3;
    s0 = fmaf(p0, av, s0); s1 = fmaf(p1, av, s1);
    s2 = fmaf(p2, av, s2); s3 = fmaf(p3, av, s3);
  }
  Ss[i*33 + jb + 0] = s0; Ss[i*33 + jb + 1] = s1;
  Ss[i*33 + jb + 2] = s2; Ss[i*33 + jb + 3] = s3;
  __syncthreads();

  if (tid < 32){
    float mx = -1e30f;
    for (int j = 0; j < 32; ++j) mx = fmaxf(mx, Ss[tid*33 + j]);
    float sum = 0.f;
    for (int j = 0; j < 32; ++j) sum += expf(Ss[tid*33 + j] - mx);
    float inv = 1.f / sum;
    for (int j = 0; j < 32; ++j) Ss[tid*33 + j] = expf(Ss[tid*33 + j] - mx) * inv;
  }
  __syncthreads();

  int c2 = tid & 127, ibase = (tid >> 7) * 16;
  float gbv = gbias[c2];
  for (int p = 0; p < 16; ++p){
    int ii = ibase + p;
    float acc = 0.f;
    #pragma unroll
    for (int j = 0; j < 32; ++j) acc = fmaf(Ss[ii*33 + j], gls[j*129 + c2], acc);
    os_[ii*129 + c2] = acc + gbv;
  }
  __syncthreads();

  int o = tid & 31, n2b = tid >> 5;
  float bfv = bfc[o];
  for (int p = 0; p < 4; ++p){
    int n2 = n2b + 8*p;
    float acc = bfv;
    for (int cc = 0; cc < 128; ++cc)
      acc = fmaf(os_[n2*129 + cc], Wfcs[o*129 + cc], acc);
    xl[((size_t)t*N_ + g*32 + n2)*O_ + o] = f2bf(acc);   // b == 0
  }
}

// ---------------- fp32 -> bf16 conversion ----------------
__global__ __launch_bounds__(256) void f2b_kernel(const float* __restrict__ in,
                                                  unsigned short* __restrict__ out, int n4){
  int idx = blockIdx.x*256 + threadIdx.x;
  if (idx >= n4) return;
  float4 v = ((const float4*)in)[idx];
  ushort4 o;
  o.x = f2bf(v.x); o.y = f2bf(v.y); o.z = f2bf(v.z); o.w = f2bf(v.w);
  ((ushort4*)out)[idx] = o;
}

// ---------------- repack1: Whh0 -> wp1[(lb*8+w)*65536 + kt*2048 + q*512 + lane*8 + j] ----------------
// wave (lb,w) owns dims lb*128+w*16+(lane&15); B-row = q*1024+dim; K = kt*32+(lane>>4)*8+j
__global__ __launch_bounds__(256) void repack1_kernel(const float* __restrict__ Whh0,
                                                      unsigned short* __restrict__ wp1){
  int tot = blockIdx.x*256 + threadIdx.x;        // < 524288
  int lane = tot & 63;
  int q    = (tot >> 6) & 3;
  int kt   = (tot >> 8) & 31;
  int wv   = (tot >> 13) & 7;
  int lb   = tot >> 16;
  int row = q*1024 + lb*128 + wv*16 + (lane & 15);
  int col = kt*32 + (lane >> 4)*8;
  *(bf16x8*)&wp1[(size_t)tot*8] = cvt8(&Whh0[(size_t)row*1024 + col]);
}

// ---------------- repack2: [Whh1|Wih1] -> wp2 (16 L2 blocks x 8 waves) ----------------
// wave (lb2,w): dims lb2*64+(w&3)*16+(lane&15); K-chunk w>>2: 0=Whh1(h2), 1=Wih1(h1)
__global__ __launch_bounds__(256) void repack2_kernel(const float* __restrict__ Whh1,
                                                      const float* __restrict__ Wih1,
                                                      unsigned short* __restrict__ wp2){
  int tot = blockIdx.x*256 + threadIdx.x;        // < 1048576
  int lane = tot & 63;
  int q    = (tot >> 6) & 3;
  int kt   = (tot >> 8) & 31;
  int wv   = (tot >> 13) & 7;
  int lb2  = tot >> 16;                          // 0..15
  int row = q*1024 + lb2*64 + (wv & 3)*16 + (lane & 15);
  int col = kt*32 + (lane >> 4)*8;
  const float* src = (wv >> 2) ? Wih1 : Whh1;
  *(bf16x8*)&wp2[(size_t)tot*8] = cvt8(&src[(size_t)row*1024 + col]);
}

// ---------------- split-K bf16 MFMA GEMM: partials for xg0 ----------------
__global__ __launch_bounds__(256) void gemm_bf2s(
    const unsigned short* __restrict__ A, const unsigned short* __restrict__ W,
    float* __restrict__ Yp, int N, int K){
  __shared__ __align__(16) short As[2][64*64];
  __shared__ __align__(16) short Bs[2][128*64];
  int tid = threadIdx.x;
  int id = blockIdx.x;
  int ks = id >> 8, rest = id & 255;
  int xcd = rest & 7, local = rest >> 3;
  int nt = xcd*4 + (local & 3), mt = local >> 2;
  int m0 = mt*64, n0 = nt*128;
  int kbase = ks * (K >> 1);
  float* Y = Yp + (size_t)ks*512*N;
  int lane = tid & 63;
  int w = tid >> 6, wm = w >> 1, wn = w & 1;
  int lr = lane & 15, ko = lane >> 4;
  int wbase = tid & ~63;

  auto STAGE = [&](int buf, int kc){
    #pragma unroll
    for (int it = 0; it < 2; ++it){
      int chunk = it*256 + tid;
      int r = chunk >> 3, c8 = chunk & 7;
      int cs = (c8 ^ (r & 7)) << 3;
      gload16(&A[(size_t)(m0 + r)*K + kc + cs], &As[buf][(size_t)(it*256 + wbase)*8]);
    }
    #pragma unroll
    for (int it = 0; it < 4; ++it){
      int chunk = it*256 + tid;
      int r = chunk >> 3, c8 = chunk & 7;
      int cs = (c8 ^ (r & 7)) << 3;
      gload16(&W[(size_t)(n0 + r)*K + kc + cs], &Bs[buf][(size_t)(it*256 + wbase)*8]);
    }
  };

  f32x4 zero = {0.f,0.f,0.f,0.f};
  f32x4 acc[2][4] = {{zero,zero,zero,zero},{zero,zero,zero,zero}};

  STAGE(0, kbase);
  __syncthreads();
  int nk = K >> 7;
  for (int kt = 0; kt < nk; ++kt){
    int cur = kt & 1;
    if (kt + 1 < nk) STAGE(cur ^ 1, kbase + ((kt + 1) << 6));
    #pragma unroll
    for (int kk = 0; kk < 2; ++kk){
      int s = kk*4 + ko;
      bf16x8 af[2], bfv[4];
      #pragma unroll
      for (int m = 0; m < 2; ++m){
        int row = wm*32 + m*16 + lr;
        af[m] = *(const bf16x8*)&As[cur][row*64 + ((s ^ (row & 7)) << 3)];
      }
      #pragma unroll
      for (int n = 0; n < 4; ++n){
        int row = wn*64 + n*16 + lr;
        bfv[n] = *(const bf16x8*)&Bs[cur][row*64 + ((s ^ (row & 7)) << 3)];
      }
      #pragma unroll
      for (int m = 0; m < 2; ++m)
        #pragma unroll
        for (int n = 0; n < 4; ++n)
          acc[m][n] = __builtin_amdgcn_mfma_f32_16x16x32_bf16(af[m], bfv[n], acc[m][n], 0, 0, 0);
    }
    __syncthreads();
  }

  #pragma unroll
  for (int m = 0; m < 2; ++m)
    #pragma unroll
    for (int n = 0; n < 4; ++n)
      #pragma unroll
      for (int v = 0; v < 4; ++v){
        int row = m0 + wm*32 + m*16 + ko*4 + v;
        int col = n0 + wn*64 + n*16 + lr;
        Y[(size_t)row*N + col] = acc[m][n][v];
      }
}

// ---------------- ksum: xg0 = p0 + p1 + bih0 + bhh0 (+ zero tag words) ----------------
__global__ __launch_bounds__(256) void ksum_kernel(
    const float* __restrict__ p0, const float* __restrict__ p1,
    const float* __restrict__ b1, const float* __restrict__ b2,
    float* __restrict__ Y, unsigned* __restrict__ syncw){
  int idx = blockIdx.x*256 + threadIdx.x;
  if (idx < NTAGW) syncw[idx] = 0u;      // syncw aliases xl_bf (dead after gemm_bf2s)
  int i4 = idx;                          // 524288 float4s
  float4 a = ((const float4*)p0)[i4];
  float4 b = ((const float4*)p1)[i4];
  int col = (i4 << 2) & 4095;
  float4 u = *(const float4*)&b1[col];
  float4 v = *(const float4*)&b2[col];
  float4 o;
  o.x = a.x + b.x + u.x + v.x;
  o.y = a.y + b.y + u.y + v.y;
  o.z = a.z + b.z + u.z + v.z;
  o.w = a.w + b.w + u.w + v.w;
  ((float4*)Y)[i4] = o;
}

// ---------------- persistent 2-layer LSTM: 24 blocks, streamed packed weights ----------------
// Blocks 0..7: layer1, 128 dims each (8 waves x 16 dims, full K=1024, 128 MFMA/wave).
// Blocks 8..23: layer2, 64 dims each (waves: 4 dim-groups x 2 K-chunks of [Whh1|Wih1],
// LDS pair-reduce). Weight rows gate-major per wave => acc tile q == gate q: all four
// gates land in the same lane (dim=lane&15, batch=(lane>>4)*4+v) -- no shuffles.
// Sync: 8+16 monotone tag lines; only wave0 polls; __syncthreads drains h stores.
__global__ __launch_bounds__(512) void lstm_persist(
    const unsigned short* __restrict__ wp1,     // packed layer1 weights (8MB)
    const unsigned short* __restrict__ wp2,     // packed layer2 weights (16MB)
    const float* __restrict__ xg0,              // [8][64][4096]
    const float* __restrict__ bih1, const float* __restrict__ bhh1,
    unsigned short* __restrict__ h1seq,         // [8][64][1024] bf16
    unsigned short* __restrict__ h2seq,         // [8][64][1024] bf16
    unsigned* __restrict__ syncw){
  __shared__ float red[4][4][64][4];            // [q][wgrp][lane][v] (layer2 reduce)
  const int tid = threadIdx.x;
  const int lane = tid & 63, w = tid >> 6;      // 8 waves
  const bool layer2 = (blockIdx.x >= L1B);
  const int lb = layer2 ? (int)blockIdx.x - L1B : (int)blockIdx.x;
  const int lr = lane & 15, ko = lane >> 4;
  const int wd = layer2 ? (w & 3) : w;          // dim-group
  const int kc = layer2 ? (w >> 2) : 1;         // layer2 K-chunk: 0=h2, 1=h1
  const int dimw = layer2 ? (lb*64 + wd*16 + lr) : (lb*128 + wd*16 + lr);
  const unsigned short* wpb = (layer2 ? wp2 : wp1) + (size_t)(lb*8 + w)*65536;

  float b2r[4] = {0.f,0.f,0.f,0.f};
  if (layer2 && w < 4){
    #pragma unroll
    for (int q = 0; q < 4; ++q) b2r[q] = bih1[q*H_ + dimw] + bhh1[q*H_ + dimw];
  }
  f32x4 creg = {0.f,0.f,0.f,0.f};
  const bf16x8 zero8 = {0,0,0,0,0,0,0,0};
  const f32x4 zf = {0.f,0.f,0.f,0.f};
  const int tt0 = layer2 ? 1 : 0, tt1 = layer2 ? 64 : 63;

  for (int tt = tt0; tt <= tt1; ++tt){
    const int tau = layer2 ? tt - 1 : tt;

    // layer1: prefetch this step's xg (independent of recurrence; hides under poll)
    float xv[4][4];
    if (!layer2 && ko < 2){
      #pragma unroll
      for (int q = 0; q < 4; ++q)
        #pragma unroll
        for (int v = 0; v < 4; ++v)
          xv[q][v] = xg0[((size_t)(ko*4 + v)*T_ + tt)*4096 + q*H_ + dimw];
    }

    // ---- wave0 polls producer tags (<=24 lines, 1/lane) ----
    if (w == 0 && (layer2 || tt > 0)){
      const unsigned* p = nullptr; unsigned need = 0;
      if (!layer2){
        if (lane < L1B){ p = syncw + TAGW(lane); need = (unsigned)tt; }
      } else {
        if (lane < L1B){ p = syncw + TAGW(lane); need = (unsigned)tt; }            // h1[tau]
        else if (lane < L1B + L2B && tt >= 2){ p = syncw + TAGW(lane); need = (unsigned)(tt - 1); } // h2[tau-1]
      }
      for (;;){
        bool ok = true;
        if (p) ok = (__hip_atomic_load(p, __ATOMIC_RELAXED, __HIP_MEMORY_SCOPE_AGENT) >= need);
        if (__all(ok)) break;
        __builtin_amdgcn_s_sleep(1);
      }
    }
    __syncthreads();

    // ---- 128 MFMA over this wave's K range (weights streamed from XCD L2) ----
    f32x4 acc0 = zf, acc1 = zf, acc2 = zf, acc3 = zf;
    const unsigned short* asrc = nullptr;
    if (!layer2){
      if (tt > 0) asrc = h1seq + ((size_t)(lr & 7)*T_ + (tt-1))*H_;
    } else if (kc == 0){
      if (tau > 0) asrc = h2seq + ((size_t)(lr & 7)*T_ + (tau-1))*H_;
    } else {
      asrc = h1seq + ((size_t)(lr & 7)*T_ + tau)*H_;
    }
    if (asrc){
      #pragma unroll 8
      for (int kt = 0; kt < 32; ++kt){
        bf16x8 av = (lr < 8) ? *(const bf16x8*)&asrc[kt*32 + ko*8] : zero8;
        const unsigned short* bb = wpb + kt*2048 + lane*8;
        acc0 = __builtin_amdgcn_mfma_f32_16x16x32_bf16(av, *(const bf16x8*)&bb[0],    acc0, 0, 0, 0);
        acc1 = __builtin_amdgcn_mfma_f32_16x16x32_bf16(av, *(const bf16x8*)&bb[512],  acc1, 0, 0, 0);
        acc2 = __builtin_amdgcn_mfma_f32_16x16x32_bf16(av, *(const bf16x8*)&bb[1024], acc2, 0, 0, 0);
        acc3 = __builtin_amdgcn_mfma_f32_16x16x32_bf16(av, *(const bf16x8*)&bb[1536], acc3, 0, 0, 0);
      }
    }

    // ---- combine + gates (all in-lane) ----
    bool gate_lane;
    float pre0[4], pre1[4], pre2[4], pre3[4];
    if (!layer2){
      gate_lane = (ko < 2);
      if (gate_lane){
        #pragma unroll
        for (int v = 0; v < 4; ++v){
          pre0[v] = acc0[v] + xv[0][v];
          pre1[v] = acc1[v] + xv[1][v];
          pre2[v] = acc2[v] + xv[2][v];
          pre3[v] = acc3[v] + xv[3][v];
        }
      }
    } else {
      if (w >= 4){
        #pragma unroll
        for (int v = 0; v < 4; ++v){
          red[0][wd][lane][v] = acc0[v];
          red[1][wd][lane][v] = acc1[v];
          red[2][wd][lane][v] = acc2[v];
          red[3][wd][lane][v] = acc3[v];
        }
      }
      __syncthreads();
      gate_lane = (w < 4) && (ko < 2);
      if (gate_lane){
        #pragma unroll
        for (int v = 0; v < 4; ++v){
          pre0[v] = acc0[v] + red[0][wd][lane][v] + b2r[0];
          pre1[v] = acc1[v] + red[1][wd][lane][v] + b2r[1];
          pre2[v] = acc2[v] + red[2][wd][lane][v] + b2r[2];
          pre3[v] = acc3[v] + red[3][wd][lane][v] + b2r[3];
        }
      }
    }

    if (gate_lane){
      unsigned short* hdst = (layer2 ? h2seq : h1seq);
      #pragma unroll
      for (int v = 0; v < 4; ++v){
        float i_ = sigf(pre0[v]), f_ = sigf(pre1[v]);
        float g_ = tanhf(pre2[v]), o_ = sigf(pre3[v]);
        float cn = fmaf(f_, creg[v], i_*g_);
        creg[v] = cn;
        float hn = o_ * tanhf(cn);
        __hip_atomic_store(&hdst[((size_t)(ko*4 + v)*T_ + tau)*H_ + dimw], f2bf(hn),
                           __ATOMIC_RELAXED, __HIP_MEMORY_SCOPE_AGENT);   // sc1 -> LLC
      }
    }
    __syncthreads();      // each wave drains its own vmcnt, then joins: h visible
    if (tid == 0)
      __hip_atomic_store(syncw + TAGW(layer2 ? (L1B + lb) : lb), (unsigned)(tau + 1),
                         __ATOMIC_RELAXED, __HIP_MEMORY_SCOPE_AGENT);
  }
}

// ---------------- final head (bf16 h2) ----------------
__global__ __launch_bounds__(128) void final_kernel(
    const unsigned short* __restrict__ h2_seq, const float* __restrict__ Wout,
    const float* __restrict__ bout, float* __restrict__ out){
  int tid = threadIdx.x;
  int b = tid >> 4, nc = tid & 15;
  const unsigned short* hp = h2_seq + ((size_t)b*T_ + (T_ - 1))*H_;
  const float* wp = Wout + nc*H_;
  float acc = bout[nc];
  for (int k = 0; k < 1024; ++k) acc = fmaf(bf2f(hp[k]), wp[k], acc);
  out[tid] = acc;
}

extern "C" void kernel_launch(void* const* d_in, const int* in_sizes, int n_in,
                              void* d_out, int out_size, void* d_ws, size_t ws_size,
                              hipStream_t stream){
  const float* X    = (const float*)d_in[0];
  const float* V    = (const float*)d_in[1];
  const float* Wl   = (const float*)d_in[2];
  const float* bl   = (const float*)d_in[3];
  const float* Wr   = (const float*)d_in[4];
  const float* br   = (const float*)d_in[5];
  const float* att  = (const float*)d_in[6];
  const float* we   = (const float*)d_in[7];
  const float* gb   = (const float*)d_in[8];
  const float* Wfc  = (const float*)d_in[9];
  const float* bfc  = (const float*)d_in[10];
  const float* Wih0 = (const float*)d_in[11];
  const float* Whh0 = (const float*)d_in[12];
  const float* bih0 = (const float*)d_in[13];
  const float* bhh0 = (const float*)d_in[14];
  const float* Wih1 = (const float*)d_in[15];
  const float* Whh1 = (const float*)d_in[16];
  const float* bih1 = (const float*)d_in[17];
  const float* bhh1 = (const float*)d_in[18];
  const float* Wout = (const float*)d_in[19];
  const float* bout = (const float*)d_in[20];

  float* ws   = (float*)d_ws;
  float* attr = ws;                     // 8192
  float* gl0  = attr + 8192;            // 2097152 (later: split-K partial slab 0)
  float* gr0  = gl0 + 2097152;          // 2097152 (later: split-K partial slab 1)
  float* xg0  = gr0 + 2097152;          // 2097152
  float* bias_comb = xg0 + 2097152;     // 64
  unsigned short* xl_bf  = (unsigned short*)(bias_comb + 64); // 4194304
  unsigned short* w0_bf  = xl_bf + 4194304;                   // 33554432
  unsigned short* wp1    = w0_bf + 33554432;                  // 4194304 (packed L1 weights)
  unsigned short* wp2    = wp1 + 4194304;                     // 8388608 (packed L2 weights)
  unsigned short* h1_bf  = wp2 + 8388608;                     // 524288
  unsigned short* h2_bf  = h1_bf + 524288;                    // 524288
  unsigned short* wlr_bf = h2_bf + 524288;                    // 16384
  unsigned short* wcomb  = wlr_bf + 16384;                    // 2048
  unsigned* syncw = (unsigned*)xl_bf;   // tags alias xl_bf (dead after gemm_bf2s)
  (void)in_sizes; (void)n_in; (void)out_size; (void)ws_size;

  attr_kernel<<<8, 256, 0, stream>>>(V, attr);
  prep_kernel<<<1, 256, 0, stream>>>(Wl, Wr, bl, gb, Wfc, bfc, wcomb, bias_comb, wlr_bf);
  gemm_proj0<<<256, 256, 0, stream>>>(X, wlr_bf, bl, br, gl0, gr0);
  attn_kernel<<<512, 256, 0, stream>>>(gl0, gr0, attr, we, att, gb, Wfc, bfc, xl_bf);
  gemm_rest<<<448, 256, 0, stream>>>(X, wcomb, bias_comb, xl_bf);

  f2b_kernel<<<32768, 256, 0, stream>>>(Wih0, w0_bf, 8388608);
  repack1_kernel<<<2048, 256, 0, stream>>>(Whh0, wp1);
  repack2_kernel<<<4096, 256, 0, stream>>>(Whh1, Wih1, wp2);

  // split-K=2 GEMM into gl0/gr0 (dead after attn), then reduce+bias into xg0
  gemm_bf2s<<<512, 256, 0, stream>>>(xl_bf, w0_bf, gl0, 4096, 8192);
  ksum_kernel<<<2048, 256, 0, stream>>>(gl0, gr0, bih0, bhh0, xg0, syncw);

  {
    void* args[] = {(void*)&wp1, (void*)&wp2, (void*)&xg0,
                    (void*)&bih1, (void*)&bhh1, (void*)&h1_bf, (void*)&h2_bf,
                    (void*)&syncw};
    hipLaunchCooperativeKernel((const void*)lstm_persist, dim3(L1B + L2B), dim3(512),
                               args, 0, stream);
  }

  final_kernel<<<1, 128, 0, stream>>>(h2_bf, Wout, bout, (float*)d_out);
}

// Round 14
// 593.429 us; speedup vs baseline: 2.3140x; 2.3140x over previous
//
#include <hip/hip_runtime.h>
#include <cmath>

#define B_ 8
#define T_ 64
#define N_ 256
#define F_ 64
#define C_ 128
#define O_ 32
#define H_ 1024
#define NC_ 16

typedef __attribute__((ext_vector_type(8))) short bf16x8;
typedef __attribute__((ext_vector_type(4))) float f32x4;

__device__ __forceinline__ float sigf(float x){ return 1.f/(1.f+expf(-x)); }

__device__ __forceinline__ unsigned short f2bf(float f){
  unsigned int u = __float_as_uint(f);
  u += 0x7fff + ((u >> 16) & 1);          // round-to-nearest-even
  return (unsigned short)(u >> 16);
}
__device__ __forceinline__ float bf2f(unsigned short s){
  return __uint_as_float(((unsigned int)s) << 16);
}

__device__ __forceinline__ void gload16(const void* g, void* l){
  __builtin_amdgcn_global_load_lds((const __attribute__((address_space(1))) void*)g,
                                   (__attribute__((address_space(3))) void*)l, 16, 0, 0);
}

__device__ __forceinline__ bf16x8 cvt8(const float* p){
  float4 a = *(const float4*)p, b = *(const float4*)(p + 4);
  bf16x8 r;
  r[0] = (short)f2bf(a.x); r[1] = (short)f2bf(a.y);
  r[2] = (short)f2bf(a.z); r[3] = (short)f2bf(a.w);
  r[4] = (short)f2bf(b.x); r[5] = (short)f2bf(b.y);
  r[6] = (short)f2bf(b.z); r[7] = (short)f2bf(b.w);
  return r;
}

// flag word for (layer l, step s, leaf i): one word per 128B line
#define FLAGW(l, s, i) ((((l)*65 + (s))*16 + (i)) << 5)
#define NFLAGW 66560          // (2*65)*16*32 words

// ---------------- K0: attr_eff[g][j][i] ----------------
__global__ __launch_bounds__(256) void attr_kernel(const float* __restrict__ V, float* __restrict__ attr){
  __shared__ float sv[32][33];
  __shared__ float selfv[32];
  int g = blockIdx.x, tid = threadIdx.x;
  for (int idx = tid; idx < 1024; idx += 256){
    int j = idx >> 5, i = idx & 31;
    sv[j][i] = sigf(V[(size_t)(g*32 + j)*256 + g*32 + i]);
  }
  __syncthreads();
  if (tid < 32){
    float s = 0.f;
    for (int j = 0; j < 32; ++j) if (j != tid) s += sv[j][tid];
    selfv[tid] = s * (1.f/31.f);
  }
  __syncthreads();
  for (int idx = tid; idx < 1024; idx += 256){
    int j = idx >> 5, i = idx & 31;
    attr[g*1024 + idx] = (j == i) ? selfv[i] : sv[j][i];
  }
}

// ---------------- prep: Wcomb = Wfc@Wl (bf16), bias_comb, Wlr_bf ----------------
__global__ __launch_bounds__(256) void prep_kernel(
    const float* __restrict__ Wl, const float* __restrict__ Wr,
    const float* __restrict__ bl, const float* __restrict__ gb,
    const float* __restrict__ Wfc, const float* __restrict__ bfc,
    unsigned short* __restrict__ wcomb,   // [32][64] bf16
    float* __restrict__ bias_comb,        // [32]
    unsigned short* __restrict__ wlr){    // [256][64] bf16
  __shared__ float wls[8192], wfcs[4096];
  int tid = threadIdx.x;
  for (int i = tid; i < 8192; i += 256) wls[i] = Wl[i];
  for (int i = tid; i < 4096; i += 256) wfcs[i] = Wfc[i];
  __syncthreads();
  for (int idx = tid; idx < 2048; idx += 256){
    int o = idx >> 6, f = idx & 63;
    float acc = 0.f;
    for (int c = 0; c < 128; ++c) acc = fmaf(wfcs[o*128 + c], wls[c*64 + f], acc);
    wcomb[idx] = f2bf(acc);
  }
  if (tid < 32){
    float acc = bfc[tid];
    for (int c = 0; c < 128; ++c) acc = fmaf(wfcs[tid*128 + c], bl[c] + gb[c], acc);
    bias_comb[tid] = acc;
  }
  for (int idx = tid; idx < 16384; idx += 256){
    int r = idx >> 6, f = idx & 63;
    wlr[idx] = f2bf(r < 128 ? wls[r*64 + f] : Wr[(r-128)*64 + f]);
  }
}

// ---------------- gemm_proj0: gl0/gr0 = X0 @ [Wl;Wr]^T (b==0 slice) ----------------
__global__ __launch_bounds__(256) void gemm_proj0(
    const float* __restrict__ X, const unsigned short* __restrict__ wlr,
    const float* __restrict__ bl, const float* __restrict__ br,
    float* __restrict__ gl0, float* __restrict__ gr0){
  int tid = threadIdx.x;
  int lane = tid & 63, w = tid >> 6;
  int lr = lane & 15, ko = lane >> 4;
  int row = blockIdx.x*64 + w*16 + lr;

  bf16x8 af[2];
  #pragma unroll
  for (int ks = 0; ks < 2; ++ks)
    af[ks] = cvt8(&X[(size_t)row*64 + ks*32 + ko*8]);

  f32x4 zero = {0.f,0.f,0.f,0.f};
  #pragma unroll 4
  for (int nt = 0; nt < 16; ++nt){
    f32x4 acc = zero;
    #pragma unroll
    for (int ks = 0; ks < 2; ++ks){
      bf16x8 bv = *(const bf16x8*)&wlr[(size_t)(nt*16 + lr)*64 + ks*32 + ko*8];
      acc = __builtin_amdgcn_mfma_f32_16x16x32_bf16(af[ks], bv, acc, 0, 0, 0);
    }
    int col = nt*16 + lr;
    #pragma unroll
    for (int v = 0; v < 4; ++v){
      int orow = blockIdx.x*64 + w*16 + ko*4 + v;
      if (col < 128) gl0[(size_t)orow*128 + col]        = acc[v] + bl[col];
      else           gr0[(size_t)orow*128 + (col-128)]  = acc[v] + br[col-128];
    }
  }
}

// ---------------- gemm_rest: xl(b>0) = X @ Wcomb^T + bias_comb ----------------
__global__ __launch_bounds__(256) void gemm_rest(
    const float* __restrict__ X, const unsigned short* __restrict__ wcomb,
    const float* __restrict__ bias_comb, unsigned short* __restrict__ xl){
  int tid = threadIdx.x;
  int lane = tid & 63, w = tid >> 6;
  int lr = lane & 15, ko = lane >> 4;
  int r0 = 16384 + blockIdx.x*256 + w*64;

  bf16x8 bv[2][2];
  #pragma unroll
  for (int nt = 0; nt < 2; ++nt)
    #pragma unroll
    for (int ks = 0; ks < 2; ++ks)
      bv[nt][ks] = *(const bf16x8*)&wcomb[(size_t)(nt*16 + lr)*64 + ks*32 + ko*8];

  f32x4 zero = {0.f,0.f,0.f,0.f};
  #pragma unroll
  for (int mt = 0; mt < 4; ++mt){
    int row = r0 + mt*16 + lr;
    bf16x8 af[2];
    #pragma unroll
    for (int ks = 0; ks < 2; ++ks)
      af[ks] = cvt8(&X[(size_t)row*64 + ks*32 + ko*8]);
    f32x4 acc0 = zero, acc1 = zero;
    #pragma unroll
    for (int ks = 0; ks < 2; ++ks){
      acc0 = __builtin_amdgcn_mfma_f32_16x16x32_bf16(af[ks], bv[0][ks], acc0, 0, 0, 0);
      acc1 = __builtin_amdgcn_mfma_f32_16x16x32_bf16(af[ks], bv[1][ks], acc1, 0, 0, 0);
    }
    #pragma unroll
    for (int v = 0; v < 4; ++v){
      int orow = r0 + mt*16 + ko*4 + v;
      xl[(size_t)orow*32 + lr]      = f2bf(acc0[v] + bias_comb[lr]);
      xl[(size_t)orow*32 + 16 + lr] = f2bf(acc1[v] + bias_comb[16 + lr]);
    }
  }
}

// ---------------- K2: attention for b==0 (+ fused fc) ----------------
__global__ __launch_bounds__(256) void attn_kernel(
    const float* __restrict__ gl0, const float* __restrict__ gr0,
    const float* __restrict__ attr, const float* __restrict__ we, const float* __restrict__ att,
    const float* __restrict__ gbias, const float* __restrict__ Wfc, const float* __restrict__ bfc,
    unsigned short* __restrict__ xl){
  __shared__ float gls[32*129], grs[32*129], os_[32*129], Wfcs[32*129];
  __shared__ float ae[32*33], Ss[32*33];
  __shared__ float wes[128], atts[128];
  int tid = threadIdx.x, blk = blockIdx.x;
  int g = blk & 7, t = blk >> 3;

  const float* glp = gl0 + ((size_t)t*N_ + g*32)*C_;
  const float* grp = gr0 + ((size_t)t*N_ + g*32)*C_;
  for (int idx = tid; idx < 4096; idx += 256){
    int n = idx >> 7, c = idx & 127;
    gls[n*129 + c]  = glp[idx];
    grs[n*129 + c]  = grp[idx];
    Wfcs[n*129 + c] = Wfc[idx];
  }
  for (int idx = tid; idx < 1024; idx += 256) ae[(idx>>5)*33 + (idx&31)] = attr[g*1024 + idx];
  if (tid < 128){ wes[tid] = we[tid]; atts[tid] = att[tid]; }
  __syncthreads();

  int i = tid >> 3, jb = (tid & 7) * 4;
  float a0 = ae[(jb+0)*33 + i], a1 = ae[(jb+1)*33 + i], a2 = ae[(jb+2)*33 + i], a3 = ae[(jb+3)*33 + i];
  float s0 = 0.f, s1 = 0.f, s2 = 0.f, s3 = 0.f;
  for (int cc = 0; cc < 128; ++cc){
    float grv = grs[i*129 + cc];
    float wv = wes[cc], av = atts[cc];
    float p0 = gls[(jb+0)*129 + cc] + grv + a0*wv;
    float p1 = gls[(jb+1)*129 + cc] + grv + a1*wv;
    float p2 = gls[(jb+2)*129 + cc] + grv + a2*wv;
    float p3 = gls[(jb+3)*129 + cc] + grv + a3*wv;
    p0 = p0 > 0.f ? p0 : 0.2f*p0;
    p1 = p1 > 0.f ? p1 : 0.2f*p1;
    p2 = p2 > 0.f ? p2 : 0.2f*p2;
    p3 = p3 > 0.f ? p3 : 0.2f*p3;
    s0 = fmaf(p0, av, s0); s1 = fmaf(p1, av, s1);
    s2 = fmaf(p2, av, s2); s3 = fmaf(p3, av, s3);
  }
  Ss[i*33 + jb + 0] = s0; Ss[i*33 + jb + 1] = s1;
  Ss[i*33 + jb + 2] = s2; Ss[i*33 + jb + 3] = s3;
  __syncthreads();

  if (tid < 32){
    float mx = -1e30f;
    for (int j = 0; j < 32; ++j) mx = fmaxf(mx, Ss[tid*33 + j]);
    float sum = 0.f;
    for (int j = 0; j < 32; ++j) sum += expf(Ss[tid*33 + j] - mx);
    float inv = 1.f / sum;
    for (int j = 0; j < 32; ++j) Ss[tid*33 + j] = expf(Ss[tid*33 + j] - mx) * inv;
  }
  __syncthreads();

  int c2 = tid & 127, ibase = (tid >> 7) * 16;
  float gbv = gbias[c2];
  for (int p = 0; p < 16; ++p){
    int ii = ibase + p;
    float acc = 0.f;
    #pragma unroll
    for (int j = 0; j < 32; ++j) acc = fmaf(Ss[ii*33 + j], gls[j*129 + c2], acc);
    os_[ii*129 + c2] = acc + gbv;
  }
  __syncthreads();

  int o = tid & 31, n2b = tid >> 5;
  float bfv = bfc[o];
  for (int p = 0; p < 4; ++p){
    int n2 = n2b + 8*p;
    float acc = bfv;
    for (int cc = 0; cc < 128; ++cc)
      acc = fmaf(os_[n2*129 + cc], Wfcs[o*129 + cc], acc);
    xl[((size_t)t*N_ + g*32 + n2)*O_ + o] = f2bf(acc);   // b == 0
  }
}

// ---------------- fp32 -> bf16 conversion ----------------
__global__ __launch_bounds__(256) void f2b_kernel(const float* __restrict__ in,
                                                  unsigned short* __restrict__ out, int n4){
  int idx = blockIdx.x*256 + threadIdx.x;
  if (idx >= n4) return;
  float4 v = ((const float4*)in)[idx];
  ushort4 o;
  o.x = f2bf(v.x); o.y = f2bf(v.y); o.z = f2bf(v.z); o.w = f2bf(v.w);
  ((ushort4*)out)[idx] = o;
}

// ---------------- w2cat: [4096][2048] = [Whh1 row | Wih1 row] bf16 ----------------
__global__ __launch_bounds__(256) void w2cat_kernel(const float* __restrict__ Whh1,
                                                    const float* __restrict__ Wih1,
                                                    unsigned short* __restrict__ w2){
  int row = blockIdx.x, tid = threadIdx.x;
  const float* a = Whh1 + (size_t)row*1024 + tid*4;
  const float* b = Wih1 + (size_t)row*1024 + tid*4;
  float4 va = *(const float4*)a, vb = *(const float4*)b;
  ushort4 oa, ob;
  oa.x = f2bf(va.x); oa.y = f2bf(va.y); oa.z = f2bf(va.z); oa.w = f2bf(va.w);
  ob.x = f2bf(vb.x); ob.y = f2bf(vb.y); ob.z = f2bf(vb.z); ob.w = f2bf(vb.w);
  *(ushort4*)&w2[(size_t)row*2048 + tid*4]        = oa;
  *(ushort4*)&w2[(size_t)row*2048 + 1024 + tid*4] = ob;
}

// ---------------- split-K bf16 MFMA GEMM: partials for xg0 ----------------
__global__ __launch_bounds__(256) void gemm_bf2s(
    const unsigned short* __restrict__ A, const unsigned short* __restrict__ W,
    float* __restrict__ Yp, int N, int K){
  __shared__ __align__(16) short As[2][64*64];
  __shared__ __align__(16) short Bs[2][128*64];
  int tid = threadIdx.x;
  int id = blockIdx.x;
  int ks = id >> 8, rest = id & 255;
  int xcd = rest & 7, local = rest >> 3;
  int nt = xcd*4 + (local & 3), mt = local >> 2;
  int m0 = mt*64, n0 = nt*128;
  int kbase = ks * (K >> 1);
  float* Y = Yp + (size_t)ks*512*N;
  int lane = tid & 63;
  int w = tid >> 6, wm = w >> 1, wn = w & 1;
  int lr = lane & 15, ko = lane >> 4;
  int wbase = tid & ~63;

  auto STAGE = [&](int buf, int kc){
    #pragma unroll
    for (int it = 0; it < 2; ++it){
      int chunk = it*256 + tid;
      int r = chunk >> 3, c8 = chunk & 7;
      int cs = (c8 ^ (r & 7)) << 3;
      gload16(&A[(size_t)(m0 + r)*K + kc + cs], &As[buf][(size_t)(it*256 + wbase)*8]);
    }
    #pragma unroll
    for (int it = 0; it < 4; ++it){
      int chunk = it*256 + tid;
      int r = chunk >> 3, c8 = chunk & 7;
      int cs = (c8 ^ (r & 7)) << 3;
      gload16(&W[(size_t)(n0 + r)*K + kc + cs], &Bs[buf][(size_t)(it*256 + wbase)*8]);
    }
  };

  f32x4 zero = {0.f,0.f,0.f,0.f};
  f32x4 acc[2][4] = {{zero,zero,zero,zero},{zero,zero,zero,zero}};

  STAGE(0, kbase);
  __syncthreads();
  int nk = K >> 7;
  for (int kt = 0; kt < nk; ++kt){
    int cur = kt & 1;
    if (kt + 1 < nk) STAGE(cur ^ 1, kbase + ((kt + 1) << 6));
    #pragma unroll
    for (int kk = 0; kk < 2; ++kk){
      int s = kk*4 + ko;
      bf16x8 af[2], bfv[4];
      #pragma unroll
      for (int m = 0; m < 2; ++m){
        int row = wm*32 + m*16 + lr;
        af[m] = *(const bf16x8*)&As[cur][row*64 + ((s ^ (row & 7)) << 3)];
      }
      #pragma unroll
      for (int n = 0; n < 4; ++n){
        int row = wn*64 + n*16 + lr;
        bfv[n] = *(const bf16x8*)&Bs[cur][row*64 + ((s ^ (row & 7)) << 3)];
      }
      #pragma unroll
      for (int m = 0; m < 2; ++m)
        #pragma unroll
        for (int n = 0; n < 4; ++n)
          acc[m][n] = __builtin_amdgcn_mfma_f32_16x16x32_bf16(af[m], bfv[n], acc[m][n], 0, 0, 0);
    }
    __syncthreads();
  }

  #pragma unroll
  for (int m = 0; m < 2; ++m)
    #pragma unroll
    for (int n = 0; n < 4; ++n)
      #pragma unroll
      for (int v = 0; v < 4; ++v){
        int row = m0 + wm*32 + m*16 + ko*4 + v;
        int col = n0 + wn*64 + n*16 + lr;
        Y[(size_t)row*N + col] = acc[m][n][v];
      }
}

// ---------------- ksum: xg0 = p0 + p1 + bih0 + bhh0 (+ zero flag words) ----------------
__global__ __launch_bounds__(256) void ksum_kernel(
    const float* __restrict__ p0, const float* __restrict__ p1,
    const float* __restrict__ b1, const float* __restrict__ b2,
    float* __restrict__ Y, unsigned* __restrict__ syncw){
  int idx = blockIdx.x*256 + threadIdx.x;
  if (idx < NFLAGW) syncw[idx] = 0u;     // syncw aliases xl_bf (dead after gemm_bf2s)
  int i4 = idx;                          // 524288 float4s
  float4 a = ((const float4*)p0)[i4];
  float4 b = ((const float4*)p1)[i4];
  int col = (i4 << 2) & 4095;
  float4 u = *(const float4*)&b1[col];
  float4 v = *(const float4*)&b2[col];
  float4 o;
  o.x = a.x + b.x + u.x + v.x;
  o.y = a.y + b.y + u.y + v.y;
  o.z = a.z + b.z + u.z + v.z;
  o.w = a.w + b.w + u.w + v.w;
  ((float4*)Y)[i4] = o;
}

// ---------------- persistent 2-layer pipelined LSTM (fence-free flag sync) ----------------
// blocks 0..127: layer1 computes h1[tt], tt=0..63; blocks 128..255: layer2 computes h2[tt-1].
// h stores are agent-scope (sc1 -> LLC); consumers use plain loads on first-touch lines.
// flag(l,s): 16 leaf counters, 8 blocks each; no root, waiters poll all 16 in parallel.
__global__ __launch_bounds__(512) void lstm_persist(
    const unsigned short* __restrict__ whh0,    // [4096][1024] bf16
    const unsigned short* __restrict__ w2cat,   // [4096][2048] bf16
    const float* __restrict__ xg0,              // [8][64][4096]
    const float* __restrict__ bih1, const float* __restrict__ bhh1,
    unsigned short* __restrict__ h1seq,         // [8][64][1024] bf16
    unsigned short* __restrict__ h2seq,         // [8][64][1024] bf16
    unsigned* __restrict__ syncw){
  __shared__ float red[4][8][64];
  const int tid = threadIdx.x;
  const int lane = tid & 63, w = tid >> 6;      // 8 waves
  const int g = w >> 2, ws = w & 3;
  const bool layer2 = (blockIdx.x >= 128);
  const int lb = layer2 ? (int)blockIdx.x - 128 : (int)blockIdx.x;
  const int lr = lane & 15, ko = lane >> 4;
  const int q = lr >> 2, dl = lr & 3;
  const int row = q*H_ + lb*8 + g*4 + dl;

  // weight fragments live in registers for all 64 steps
  bf16x8 wreg[16];
  if (!layer2){
    const unsigned short* wrow = whh0 + (size_t)row*1024 + ws*256;
    #pragma unroll
    for (int kk = 0; kk < 8; ++kk) wreg[kk] = *(const bf16x8*)&wrow[kk*32 + ko*8];
  } else {
    const unsigned short* wrow = w2cat + (size_t)row*2048 + ws*512;
    #pragma unroll
    for (int kk = 0; kk < 16; ++kk) wreg[kk] = *(const bf16x8*)&wrow[kk*32 + ko*8];
  }

  const int g2 = tid >> 5, bt = (tid >> 2) & 7, dl2 = tid & 3;
  const int dimt = lb*8 + g2*4 + dl2;
  float creg = 0.f;
  float b2r[4] = {0.f,0.f,0.f,0.f};
  if (layer2 && tid < 64){
    #pragma unroll
    for (int qq = 0; qq < 4; ++qq) b2r[qq] = bih1[qq*H_ + dimt] + bhh1[qq*H_ + dimt];
  }
  const bf16x8 zero8 = {0,0,0,0,0,0,0,0};

  for (int tt = 0; tt <= 64; ++tt){
    const int tau = layer2 ? tt - 1 : tt;
    const bool active = layer2 ? (tt >= 1) : (tt < 64);

    // ---- wait for producer flags (wave 0 polls, lanes in parallel) ----
    if (w == 0){
      int s1 = -1, s2 = -1;
      if (!layer2){ if (tt > 0 && tt < 64) s1 = tt - 1; }  // need h1[tt-1]
      else if (tt >= 1){ s1 = tau; s2 = tau - 1; }         // need h1[tau], h2[tau-1]
      if (s1 >= 0){
        unsigned* p1 = syncw + FLAGW(0, s1, lane & 15);
        unsigned* p2 = (s2 >= 0) ? (syncw + FLAGW(1, s2, lane & 15)) : (unsigned*)0;
        for (;;){
          unsigned v = 8u;
          if (lane < 16)            v = __hip_atomic_load(p1, __ATOMIC_RELAXED, __HIP_MEMORY_SCOPE_AGENT);
          else if (lane < 32 && p2) v = __hip_atomic_load(p2, __ATOMIC_RELAXED, __HIP_MEMORY_SCOPE_AGENT);
          if (__all(v >= 8u)) break;
          __builtin_amdgcn_s_sleep(1);
        }
      }
    }
    __syncthreads();

    f32x4 accv = {0.f,0.f,0.f,0.f};
    if (active){
      const unsigned short* arow = nullptr;
      if (!layer2){
        if (tt > 0) arow = h1seq + ((size_t)(lr & 7)*T_ + (tt-1))*H_ + ws*256;
      } else {
        if (ws < 2){ if (tau > 0) arow = h2seq + ((size_t)(lr & 7)*T_ + (tau-1))*H_ + ws*512; }
        else         arow = h1seq + ((size_t)(lr & 7)*T_ + tau)*H_ + (ws-2)*512;
      }
      if (arow){
        f32x4 acc2 = {0.f,0.f,0.f,0.f};
        if (!layer2){
          #pragma unroll
          for (int kk = 0; kk < 8; ++kk){
            bf16x8 av = (lr < 8) ? *(const bf16x8*)&arow[kk*32 + ko*8] : zero8;
            if (kk & 1) acc2 = __builtin_amdgcn_mfma_f32_16x16x32_bf16(av, wreg[kk], acc2, 0, 0, 0);
            else        accv = __builtin_amdgcn_mfma_f32_16x16x32_bf16(av, wreg[kk], accv, 0, 0, 0);
          }
        } else {
          #pragma unroll
          for (int kk = 0; kk < 16; ++kk){
            bf16x8 av = (lr < 8) ? *(const bf16x8*)&arow[kk*32 + ko*8] : zero8;
            if (kk & 1) acc2 = __builtin_amdgcn_mfma_f32_16x16x32_bf16(av, wreg[kk], acc2, 0, 0, 0);
            else        accv = __builtin_amdgcn_mfma_f32_16x16x32_bf16(av, wreg[kk], accv, 0, 0, 0);
          }
        }
        accv = accv + acc2;
      }
    }
    #pragma unroll
    for (int v = 0; v < 4; ++v) red[v][w][lane] = accv[v];
    __syncthreads();

    if (active && tid < 64){
      float pre[4];
      #pragma unroll
      for (int qq = 0; qq < 4; ++qq){
        int lsrc = (bt >> 2)*16 + qq*4 + dl2, v = bt & 3;
        pre[qq] = red[v][g2*4+0][lsrc] + red[v][g2*4+1][lsrc]
                + red[v][g2*4+2][lsrc] + red[v][g2*4+3][lsrc];
      }
      float pi, pf, pg, po;
      if (!layer2){
        size_t xb = ((size_t)bt*T_ + tt)*4096;
        pi = pre[0] + xg0[xb + 0*H_ + dimt];
        pf = pre[1] + xg0[xb + 1*H_ + dimt];
        pg = pre[2] + xg0[xb + 2*H_ + dimt];
        po = pre[3] + xg0[xb + 3*H_ + dimt];
      } else {
        pi = pre[0] + b2r[0]; pf = pre[1] + b2r[1];
        pg = pre[2] + b2r[2]; po = pre[3] + b2r[3];
      }
      float i_ = sigf(pi), f_ = sigf(pf), g_ = tanhf(pg), o_ = sigf(po);
      float cn = fmaf(f_, creg, i_*g_);
      creg = cn;
      float hn = o_ * tanhf(cn);
      unsigned short* hp = (layer2 ? h2seq : h1seq) + ((size_t)bt*T_ + tau)*H_ + dimt;
      __hip_atomic_store(hp, f2bf(hn), __ATOMIC_RELAXED, __HIP_MEMORY_SCOPE_AGENT);  // sc1 -> LLC
    }
    __syncthreads();                    // drains h stores (vmcnt) before arrival

    if (active && tid == 0){
      const int fl = layer2 ? 1 : 0;
      const int s  = layer2 ? tau : tt;
      __hip_atomic_fetch_add(syncw + FLAGW(fl, s, lb & 15), 1u,
                             __ATOMIC_RELAXED, __HIP_MEMORY_SCOPE_AGENT);
    }
  }
}

// ---------------- final head (bf16 h2) ----------------
__global__ __launch_bounds__(128) void final_kernel(
    const unsigned short* __restrict__ h2_seq, const float* __restrict__ Wout,
    const float* __restrict__ bout, float* __restrict__ out){
  int tid = threadIdx.x;
  int b = tid >> 4, nc = tid & 15;
  const unsigned short* hp = h2_seq + ((size_t)b*T_ + (T_ - 1))*H_;
  const float* wp = Wout + nc*H_;
  float acc = bout[nc];
  for (int k = 0; k < 1024; ++k) acc = fmaf(bf2f(hp[k]), wp[k], acc);
  out[tid] = acc;
}

extern "C" void kernel_launch(void* const* d_in, const int* in_sizes, int n_in,
                              void* d_out, int out_size, void* d_ws, size_t ws_size,
                              hipStream_t stream){
  const float* X    = (const float*)d_in[0];
  const float* V    = (const float*)d_in[1];
  const float* Wl   = (const float*)d_in[2];
  const float* bl   = (const float*)d_in[3];
  const float* Wr   = (const float*)d_in[4];
  const float* br   = (const float*)d_in[5];
  const float* att  = (const float*)d_in[6];
  const float* we   = (const float*)d_in[7];
  const float* gb   = (const float*)d_in[8];
  const float* Wfc  = (const float*)d_in[9];
  const float* bfc  = (const float*)d_in[10];
  const float* Wih0 = (const float*)d_in[11];
  const float* Whh0 = (const float*)d_in[12];
  const float* bih0 = (const float*)d_in[13];
  const float* bhh0 = (const float*)d_in[14];
  const float* Wih1 = (const float*)d_in[15];
  const float* Whh1 = (const float*)d_in[16];
  const float* bih1 = (const float*)d_in[17];
  const float* bhh1 = (const float*)d_in[18];
  const float* Wout = (const float*)d_in[19];
  const float* bout = (const float*)d_in[20];

  float* ws   = (float*)d_ws;
  float* attr = ws;                     // 8192
  float* gl0  = attr + 8192;            // 2097152 (later: split-K partial slab 0)
  float* gr0  = gl0 + 2097152;          // 2097152 (later: split-K partial slab 1)
  float* xg0  = gr0 + 2097152;          // 2097152
  float* bias_comb = xg0 + 2097152;     // 64
  unsigned short* xl_bf  = (unsigned short*)(bias_comb + 64); // 4194304
  unsigned short* w0_bf  = xl_bf + 4194304;                   // 33554432
  unsigned short* wh0_bf = w0_bf + 33554432;                  // 4194304
  unsigned short* w2_bf  = wh0_bf + 4194304;                  // 8388608
  unsigned short* h1_bf  = w2_bf + 8388608;                   // 524288
  unsigned short* h2_bf  = h1_bf + 524288;                    // 524288
  unsigned short* wlr_bf = h2_bf + 524288;                    // 16384
  unsigned short* wcomb  = wlr_bf + 16384;                    // 2048
  unsigned* syncw = (unsigned*)xl_bf;   // flags alias xl_bf (dead after gemm_bf2s)
  (void)in_sizes; (void)n_in; (void)out_size; (void)ws_size;

  attr_kernel<<<8, 256, 0, stream>>>(V, attr);
  prep_kernel<<<1, 256, 0, stream>>>(Wl, Wr, bl, gb, Wfc, bfc, wcomb, bias_comb, wlr_bf);
  gemm_proj0<<<256, 256, 0, stream>>>(X, wlr_bf, bl, br, gl0, gr0);
  attn_kernel<<<512, 256, 0, stream>>>(gl0, gr0, attr, we, att, gb, Wfc, bfc, xl_bf);
  gemm_rest<<<448, 256, 0, stream>>>(X, wcomb, bias_comb, xl_bf);

  f2b_kernel<<<32768, 256, 0, stream>>>(Wih0, w0_bf, 8388608);
  f2b_kernel<<<4096, 256, 0, stream>>>(Whh0, wh0_bf, 1048576);
  w2cat_kernel<<<4096, 256, 0, stream>>>(Whh1, Wih1, w2_bf);

  // split-K=2 GEMM into gl0/gr0 (dead after attn), then reduce+bias into xg0
  gemm_bf2s<<<512, 256, 0, stream>>>(xl_bf, w0_bf, gl0, 4096, 8192);
  ksum_kernel<<<2048, 256, 0, stream>>>(gl0, gr0, bih0, bhh0, xg0, syncw);

  {
    void* args[] = {(void*)&wh0_bf, (void*)&w2_bf, (void*)&xg0,
                    (void*)&bih1, (void*)&bhh1, (void*)&h1_bf, (void*)&h2_bf,
                    (void*)&syncw};
    hipLaunchCooperativeKernel((const void*)lstm_persist, dim3(256), dim3(512),
                               args, 0, stream);
  }

  final_kernel<<<1, 128, 0, stream>>>(h2_bf, Wout, bout, (float*)d_out);
}